// Round 9
// baseline (5500.442 us; speedup 1.0000x reference)
//
#include <hip/hip_runtime.h>

#define TT 256
#define BB 4096
#define EPB 2   // batch elements per block

__device__ __forceinline__ float sigm(float x) {
  float e = __expf(-x);
  return __builtin_amdgcn_rcpf(1.0f + e);
}

__device__ __forceinline__ float tanhx(float x) {
  x = fminf(15.0f, fmaxf(-15.0f, x));
  float e = __expf(-2.0f * x);
  return (1.0f - e) * __builtin_amdgcn_rcpf(1.0f + e);
}

#define DOT4(acc, wv, xv)                 \
  do {                                    \
    acc = fmaf((wv).x, (xv).x, acc);      \
    acc = fmaf((wv).y, (xv).y, acc);      \
    acc = fmaf((wv).z, (xv).z, acc);      \
    acc = fmaf((wv).w, (xv).w, acc);      \
  } while (0)

// Block = 128 threads (2 waves), EPB=2. Wave w = direction w, both elements.
// Register demand ~252 (round 7 measured): W_hh resident 192 + accs/misc.
// amdgpu_waves_per_eu(2,2): round 7 proved the allocator gives ~252 regs for
// 128-thread blocks (LDS 34 KB -> 4 blocks/CU -> 8 waves/CU -> 2/SIMD natural
// budget = 256). Round 7's (1,1) attribute then CAPPED residency at 1 wave/SIMD,
// exposing all scan latency (25% issue efficiency). 252*2 = 504 <= 512-reg
// file: 2 waves/SIMD are architecturally allowed -> let them co-reside so the
// co-wave's independent scan hides LDS/L1/transcendental latency.
//   round 5/6 (256-thr blocks): LDS allowed 16 waves/CU -> allocator targeted
//   128 regs -> W_hh spilled (WRITE_SIZE 420 MB). 128-thr blocks avoid that.
// W_ih (48 floats) streams from L1 via laundered pointer (defeats LICM).
__global__ __launch_bounds__(128) __attribute__((amdgpu_waves_per_eu(2, 2)))
void gru_fused(
    const float* __restrict__ xin,    // [B][T][2]
    const float* __restrict__ wih1,   // [48][2]
    const float* __restrict__ whh1,   // [48][16]
    const float* __restrict__ bih1,   // [48]
    const float* __restrict__ bhh1,   // [48]
    const float* __restrict__ wihf,   // [192][16]
    const float* __restrict__ whhf,   // [192][64]
    const float* __restrict__ bihf,   // [192]
    const float* __restrict__ bhhf,   // [192]
    const float* __restrict__ wihb,
    const float* __restrict__ whhb,
    const float* __restrict__ bihb,
    const float* __restrict__ bhhb,
    const float* __restrict__ W1,     // [32][64]
    const float* __restrict__ b1,     // [32]
    const float* __restrict__ W2,     // [8][32]
    const float* __restrict__ b2,     // [8]
    float* __restrict__ zout)         // [B][8]
{
  __shared__ __align__(16) float out1L[EPB][TT][16];  // 32 KB layer-1 outputs
  __shared__ __align__(16) float hs[2][EPB][64];      // [dir][elem][unit]
  __shared__ __align__(16) float hl1[EPB][16];        // layer-1 running h
  __shared__ __align__(16) float ys[EPB][32];         // MLP hidden

  const int tid = threadIdx.x;
  const int w   = tid >> 6;    // wave 0..1 = direction (0=fwd, 1=bwd)
  const int l   = tid & 63;
  const int b0  = blockIdx.x * EPB;

  // ---------------- phase 1: layer-1 GRU; wave w does element w ----------------
  if (l < 16) {
    const int u  = l;
    const int e1 = w;

    float wr[16], wz[16], wn[16];
#pragma unroll
    for (int j = 0; j < 16; ++j) {
      wr[j] = whh1[u * 16 + j];
      wz[j] = whh1[(16 + u) * 16 + j];
      wn[j] = whh1[(32 + u) * 16 + j];
    }
    const float wir0 = wih1[2 * u],        wir1 = wih1[2 * u + 1];
    const float wiz0 = wih1[2 * (16 + u)], wiz1 = wih1[2 * (16 + u) + 1];
    const float win0 = wih1[2 * (32 + u)], win1 = wih1[2 * (32 + u) + 1];
    const float br  = bih1[u] + bhh1[u];
    const float bz  = bih1[16 + u] + bhh1[16 + u];
    const float bin = bih1[32 + u];
    const float bhn = bhh1[32 + u];

    const float2* xp = (const float2*)xin + (size_t)(b0 + e1) * TT;

    float h = 0.0f;
    hl1[e1][u] = 0.0f;
    for (int t = 0; t < TT; ++t) {
      float2 xv = xp[t];
      float ar = fmaf(wir1, xv.y, fmaf(wir0, xv.x, br));
      float az = fmaf(wiz1, xv.y, fmaf(wiz0, xv.x, bz));
      float an = fmaf(win1, xv.y, fmaf(win0, xv.x, bin));
      float hr = 0.f, hz = 0.f, hn = bhn;
#pragma unroll
      for (int j = 0; j < 16; ++j) {
        float hj = hl1[e1][j];
        hr = fmaf(wr[j], hj, hr);
        hz = fmaf(wz[j], hj, hz);
        hn = fmaf(wn[j], hj, hn);
      }
      float r = sigm(ar + hr);
      float z = sigm(az + hz);
      float n = tanhx(fmaf(r, hn, an));
      h = fmaf(z, h - n, n);   // (1-z)*n + z*h
      hl1[e1][u] = h;
      out1L[e1][t][u] = h;
    }
  }
  __syncthreads();

  // ---------------- phase 2: layer-2 scan; wave w = dir, elems 0,1 ----------------
  const float* wih = w ? wihb : wihf;
  const float* whh = w ? whhb : whhf;
  const float* bih = w ? bihb : bihf;
  const float* bhh = w ? bhhb : bhhf;

  // W_hh rows l / 64+l / 128+l : 192 fp32, VGPR-resident for the whole scan.
  float4 wr2[16], wz2[16], wn2[16];
  {
    const float4* whh4 = (const float4*)whh;
#pragma unroll
    for (int j4 = 0; j4 < 16; ++j4) {
      wr2[j4] = whh4[l * 16 + j4];
      wz2[j4] = whh4[(64 + l) * 16 + j4];
      wn2[j4] = whh4[(128 + l) * 16 + j4];
    }
  }
  const float br2  = bih[l] + bhh[l];
  const float bz2  = bih[64 + l] + bhh[64 + l];
  const float bin2 = bih[128 + l];
  const float bhn2 = bhh[128 + l];

  float h0 = 0.f, h1 = 0.f;   // running h for elems 0,1 (this dir)
  hs[w][0][l] = 0.f;
  hs[w][1][l] = 0.f;

  const float4* wp = (const float4*)wih;  // laundered each iter: stays an L1 stream

  for (int t2 = 0; t2 < TT / 2; ++t2) {
    // defeat LICM: without this the compiler hoists the 12 W_ih float4 loads
    // into 48 loop-carried VGPRs -> demand ~300 > 256 -> scratch spill (round 4).
    asm volatile("" : "+v"(wp));
    const int ta = w ? (TT - 1 - 2 * t2) : (2 * t2);
    const int tb = w ? (ta - 1) : (ta + 1);
    const float4* xa0 = (const float4*)&out1L[0][ta][0];
    const float4* xa1 = (const float4*)&out1L[1][ta][0];
    const float4* xb0 = (const float4*)&out1L[0][tb][0];
    const float4* xb1 = (const float4*)&out1L[1][tb][0];

    // input projections for steps A,B x elems 0,1 share one W_ih pass
    float arA0 = br2, azA0 = bz2, anA0 = bin2;
    float arA1 = br2, azA1 = bz2, anA1 = bin2;
    float arB0 = br2, azB0 = bz2, anB0 = bin2;
    float arB1 = br2, azB1 = bz2, anB1 = bin2;
#pragma unroll
    for (int i4 = 0; i4 < 4; ++i4) {
      const float4 wrv = wp[l * 4 + i4];
      const float4 wzv = wp[(64 + l) * 4 + i4];
      const float4 wnv = wp[(128 + l) * 4 + i4];
      const float4 va0 = xa0[i4];
      const float4 va1 = xa1[i4];
      const float4 vb0 = xb0[i4];
      const float4 vb1 = xb1[i4];
      DOT4(arA0, wrv, va0); DOT4(azA0, wzv, va0); DOT4(anA0, wnv, va0);
      DOT4(arA1, wrv, va1); DOT4(azA1, wzv, va1); DOT4(anA1, wnv, va1);
      DOT4(arB0, wrv, vb0); DOT4(azB0, wzv, vb0); DOT4(anB0, wnv, vb0);
      DOT4(arB1, wrv, vb1); DOT4(azB1, wzv, vb1); DOT4(anB1, wnv, vb1);
    }

    // ---- step A ----
    {
      float hr0 = 0.f, hz0 = 0.f, hn0 = bhn2;
      float hr1 = 0.f, hz1 = 0.f, hn1 = bhn2;
#pragma unroll
      for (int j4 = 0; j4 < 16; ++j4) {
        const float4 ha = *(const float4*)&hs[w][0][j4 * 4];  // uniform broadcast
        const float4 hb = *(const float4*)&hs[w][1][j4 * 4];
        const float4 wrv = wr2[j4], wzv = wz2[j4], wnv = wn2[j4];
        DOT4(hr0, wrv, ha); DOT4(hz0, wzv, ha); DOT4(hn0, wnv, ha);
        DOT4(hr1, wrv, hb); DOT4(hz1, wzv, hb); DOT4(hn1, wnv, hb);
      }
      { float r = sigm(arA0 + hr0), z = sigm(azA0 + hz0);
        float n = tanhx(fmaf(r, hn0, anA0)); h0 = fmaf(z, h0 - n, n); }
      { float r = sigm(arA1 + hr1), z = sigm(azA1 + hz1);
        float n = tanhx(fmaf(r, hn1, anA1)); h1 = fmaf(z, h1 - n, n); }
      hs[w][0][l] = h0;   // own-wave write; in-order DS pipe orders vs step B reads
      hs[w][1][l] = h1;
    }
    // ---- step B ----
    {
      float hr0 = 0.f, hz0 = 0.f, hn0 = bhn2;
      float hr1 = 0.f, hz1 = 0.f, hn1 = bhn2;
#pragma unroll
      for (int j4 = 0; j4 < 16; ++j4) {
        const float4 ha = *(const float4*)&hs[w][0][j4 * 4];
        const float4 hb = *(const float4*)&hs[w][1][j4 * 4];
        const float4 wrv = wr2[j4], wzv = wz2[j4], wnv = wn2[j4];
        DOT4(hr0, wrv, ha); DOT4(hz0, wzv, ha); DOT4(hn0, wnv, ha);
        DOT4(hr1, wrv, hb); DOT4(hz1, wzv, hb); DOT4(hn1, wnv, hb);
      }
      { float r = sigm(arB0 + hr0), z = sigm(azB0 + hz0);
        float n = tanhx(fmaf(r, hn0, anB0)); h0 = fmaf(z, h0 - n, n); }
      { float r = sigm(arB1 + hr1), z = sigm(azB1 + hz1);
        float n = tanhx(fmaf(r, hn1, anB1)); h1 = fmaf(z, h1 - n, n); }
      hs[w][0][l] = h0;
      hs[w][1][l] = h1;
    }
  }
  __syncthreads();

  // ---------------- phase 3: h = h_fwd + h_bwd; MLP 64->32->8; wave w -> elem w ----------------
  if (l < 32) {
    const int s = l;
    float acc = b1[s];
    const float4* w1r = (const float4*)(W1 + s * 64);
#pragma unroll
    for (int j4 = 0; j4 < 16; ++j4) {
      const float4 hv0 = *(const float4*)&hs[0][w][j4 * 4];  // fwd, elem w
      const float4 hv1 = *(const float4*)&hs[1][w][j4 * 4];  // bwd, elem w
      const float4 wv  = w1r[j4];
      acc = fmaf(wv.x, hv0.x + hv1.x, acc);
      acc = fmaf(wv.y, hv0.y + hv1.y, acc);
      acc = fmaf(wv.z, hv0.z + hv1.z, acc);
      acc = fmaf(wv.w, hv0.w + hv1.w, acc);
    }
    ys[w][s] = acc;
  }
  // same-wave LDS write->read: in-order, no barrier needed
  if (l < 8) {
    float acc = b2[l];
#pragma unroll
    for (int j4 = 0; j4 < 8; ++j4) {
      const float4 yv = *(const float4*)&ys[w][j4 * 4];
      const float4 wv = *(const float4*)&W2[l * 32 + j4 * 4];
      DOT4(acc, wv, yv);
    }
    zout[(b0 + w) * 8 + l] = acc;
  }
}

extern "C" void kernel_launch(void* const* d_in, const int* in_sizes, int n_in,
                              void* d_out, int out_size, void* d_ws, size_t ws_size,
                              hipStream_t stream) {
  const float* all_traj = (const float*)d_in[0];
  const float* w_ih1  = (const float*)d_in[1];
  const float* w_hh1  = (const float*)d_in[2];
  const float* b_ih1  = (const float*)d_in[3];
  const float* b_hh1  = (const float*)d_in[4];
  const float* w_ih2f = (const float*)d_in[5];
  const float* w_hh2f = (const float*)d_in[6];
  const float* b_ih2f = (const float*)d_in[7];
  const float* b_hh2f = (const float*)d_in[8];
  const float* w_ih2b = (const float*)d_in[9];
  const float* w_hh2b = (const float*)d_in[10];
  const float* b_ih2b = (const float*)d_in[11];
  const float* b_hh2b = (const float*)d_in[12];
  const float* W1 = (const float*)d_in[13];
  const float* b1 = (const float*)d_in[14];
  const float* W2 = (const float*)d_in[15];
  const float* b2 = (const float*)d_in[16];
  float* z = (float*)d_out;

  // 2048 blocks x 128 threads (2 waves): wave = direction, 2 elements per wave
  gru_fused<<<BB / EPB, 128, 0, stream>>>(
      all_traj, w_ih1, w_hh1, b_ih1, b_hh1,
      w_ih2f, w_hh2f, b_ih2f, b_hh2f,
      w_ih2b, w_hh2b, b_ih2b, b_hh2b,
      W1, b1, W2, b2, z);
}

// Round 10
// 2027.171 us; speedup vs baseline: 2.7134x; 2.7134x over previous
//
#include <hip/hip_runtime.h>

#define TT 256
#define BB 4096
#define EPB 2   // batch elements per block

__device__ __forceinline__ float sigm(float x) {
  float e = __expf(-x);
  return __builtin_amdgcn_rcpf(1.0f + e);
}

__device__ __forceinline__ float tanhx(float x) {
  x = fminf(15.0f, fmaxf(-15.0f, x));
  float e = __expf(-2.0f * x);
  return (1.0f - e) * __builtin_amdgcn_rcpf(1.0f + e);
}

#define DOT4(acc, wv, xv)                 \
  do {                                    \
    acc = fmaf((wv).x, (xv).x, acc);      \
    acc = fmaf((wv).y, (xv).y, acc);      \
    acc = fmaf((wv).z, (xv).z, acc);      \
    acc = fmaf((wv).w, (xv).w, acc);      \
  } while (0)

// Block = 128 threads (2 waves), EPB=2. Wave w = direction w, both elements.
// amdgpu_waves_per_eu(1, 2):
//   min=1 -> allocator keeps the 256-reg budget that round 7 proved gives
//            VGPR=252 with ZERO spill (W_hh fully register-resident);
//   max=2 -> unlike round 7's (1,1), the HW may co-schedule a second wave
//            per SIMD: 2 x 252 = 504 <= 512-reg file, LDS 34KB x 4 blocks
//            <= 160KB, 8 waves x 252 <= 2048 regs/CU -- all fit.
// History: (1,1)=252 regs no-spill but 1 wave/SIMD latency-exposed (2034us);
//          (2,2)=128 regs, total spill to HBM (5500us); lb(128,2)=200 regs,
//          W_hh L2-streamed every step (1455us). The co-wave is what fills
//          round 7's ~75% stall (LDS h round-trip, L1 W_ih, exp chains).
// W_ih (48 floats) streams from L1 via laundered pointer (defeats LICM).
__global__ __launch_bounds__(128) __attribute__((amdgpu_waves_per_eu(1, 2)))
void gru_fused(
    const float* __restrict__ xin,    // [B][T][2]
    const float* __restrict__ wih1,   // [48][2]
    const float* __restrict__ whh1,   // [48][16]
    const float* __restrict__ bih1,   // [48]
    const float* __restrict__ bhh1,   // [48]
    const float* __restrict__ wihf,   // [192][16]
    const float* __restrict__ whhf,   // [192][64]
    const float* __restrict__ bihf,   // [192]
    const float* __restrict__ bhhf,   // [192]
    const float* __restrict__ wihb,
    const float* __restrict__ whhb,
    const float* __restrict__ bihb,
    const float* __restrict__ bhhb,
    const float* __restrict__ W1,     // [32][64]
    const float* __restrict__ b1,     // [32]
    const float* __restrict__ W2,     // [8][32]
    const float* __restrict__ b2,     // [8]
    float* __restrict__ zout)         // [B][8]
{
  __shared__ __align__(16) float out1L[EPB][TT][16];  // 32 KB layer-1 outputs
  __shared__ __align__(16) float hs[2][EPB][64];      // [dir][elem][unit]
  __shared__ __align__(16) float hl1[EPB][16];        // layer-1 running h
  __shared__ __align__(16) float ys[EPB][32];         // MLP hidden

  const int tid = threadIdx.x;
  const int w   = tid >> 6;    // wave 0..1 = direction (0=fwd, 1=bwd)
  const int l   = tid & 63;
  const int b0  = blockIdx.x * EPB;

  // ---------------- phase 1: layer-1 GRU; wave w does element w ----------------
  if (l < 16) {
    const int u  = l;
    const int e1 = w;

    float wr[16], wz[16], wn[16];
#pragma unroll
    for (int j = 0; j < 16; ++j) {
      wr[j] = whh1[u * 16 + j];
      wz[j] = whh1[(16 + u) * 16 + j];
      wn[j] = whh1[(32 + u) * 16 + j];
    }
    const float wir0 = wih1[2 * u],        wir1 = wih1[2 * u + 1];
    const float wiz0 = wih1[2 * (16 + u)], wiz1 = wih1[2 * (16 + u) + 1];
    const float win0 = wih1[2 * (32 + u)], win1 = wih1[2 * (32 + u) + 1];
    const float br  = bih1[u] + bhh1[u];
    const float bz  = bih1[16 + u] + bhh1[16 + u];
    const float bin = bih1[32 + u];
    const float bhn = bhh1[32 + u];

    const float2* xp = (const float2*)xin + (size_t)(b0 + e1) * TT;

    float h = 0.0f;
    hl1[e1][u] = 0.0f;
    for (int t = 0; t < TT; ++t) {
      float2 xv = xp[t];
      float ar = fmaf(wir1, xv.y, fmaf(wir0, xv.x, br));
      float az = fmaf(wiz1, xv.y, fmaf(wiz0, xv.x, bz));
      float an = fmaf(win1, xv.y, fmaf(win0, xv.x, bin));
      float hr = 0.f, hz = 0.f, hn = bhn;
#pragma unroll
      for (int j = 0; j < 16; ++j) {
        float hj = hl1[e1][j];
        hr = fmaf(wr[j], hj, hr);
        hz = fmaf(wz[j], hj, hz);
        hn = fmaf(wn[j], hj, hn);
      }
      float r = sigm(ar + hr);
      float z = sigm(az + hz);
      float n = tanhx(fmaf(r, hn, an));
      h = fmaf(z, h - n, n);   // (1-z)*n + z*h
      hl1[e1][u] = h;
      out1L[e1][t][u] = h;
    }
  }
  __syncthreads();

  // ---------------- phase 2: layer-2 scan; wave w = dir, elems 0,1 ----------------
  const float* wih = w ? wihb : wihf;
  const float* whh = w ? whhb : whhf;
  const float* bih = w ? bihb : bihf;
  const float* bhh = w ? bhhb : bhhf;

  // W_hh rows l / 64+l / 128+l : 192 fp32, VGPR-resident for the whole scan.
  float4 wr2[16], wz2[16], wn2[16];
  {
    const float4* whh4 = (const float4*)whh;
#pragma unroll
    for (int j4 = 0; j4 < 16; ++j4) {
      wr2[j4] = whh4[l * 16 + j4];
      wz2[j4] = whh4[(64 + l) * 16 + j4];
      wn2[j4] = whh4[(128 + l) * 16 + j4];
    }
  }
  const float br2  = bih[l] + bhh[l];
  const float bz2  = bih[64 + l] + bhh[64 + l];
  const float bin2 = bih[128 + l];
  const float bhn2 = bhh[128 + l];

  float h0 = 0.f, h1 = 0.f;   // running h for elems 0,1 (this dir)
  hs[w][0][l] = 0.f;
  hs[w][1][l] = 0.f;

  const float4* wp = (const float4*)wih;  // laundered each iter: stays an L1 stream

  for (int t2 = 0; t2 < TT / 2; ++t2) {
    // defeat LICM: without this the compiler hoists the 12 W_ih float4 loads
    // into 48 loop-carried VGPRs -> demand ~300 > 256 -> scratch spill (round 4).
    asm volatile("" : "+v"(wp));
    const int ta = w ? (TT - 1 - 2 * t2) : (2 * t2);
    const int tb = w ? (ta - 1) : (ta + 1);
    const float4* xa0 = (const float4*)&out1L[0][ta][0];
    const float4* xa1 = (const float4*)&out1L[1][ta][0];
    const float4* xb0 = (const float4*)&out1L[0][tb][0];
    const float4* xb1 = (const float4*)&out1L[1][tb][0];

    // input projections for steps A,B x elems 0,1 share one W_ih pass
    float arA0 = br2, azA0 = bz2, anA0 = bin2;
    float arA1 = br2, azA1 = bz2, anA1 = bin2;
    float arB0 = br2, azB0 = bz2, anB0 = bin2;
    float arB1 = br2, azB1 = bz2, anB1 = bin2;
#pragma unroll
    for (int i4 = 0; i4 < 4; ++i4) {
      const float4 wrv = wp[l * 4 + i4];
      const float4 wzv = wp[(64 + l) * 4 + i4];
      const float4 wnv = wp[(128 + l) * 4 + i4];
      const float4 va0 = xa0[i4];
      const float4 va1 = xa1[i4];
      const float4 vb0 = xb0[i4];
      const float4 vb1 = xb1[i4];
      DOT4(arA0, wrv, va0); DOT4(azA0, wzv, va0); DOT4(anA0, wnv, va0);
      DOT4(arA1, wrv, va1); DOT4(azA1, wzv, va1); DOT4(anA1, wnv, va1);
      DOT4(arB0, wrv, vb0); DOT4(azB0, wzv, vb0); DOT4(anB0, wnv, vb0);
      DOT4(arB1, wrv, vb1); DOT4(azB1, wzv, vb1); DOT4(anB1, wnv, vb1);
    }

    // ---- step A ----
    {
      float hr0 = 0.f, hz0 = 0.f, hn0 = bhn2;
      float hr1 = 0.f, hz1 = 0.f, hn1 = bhn2;
#pragma unroll
      for (int j4 = 0; j4 < 16; ++j4) {
        const float4 ha = *(const float4*)&hs[w][0][j4 * 4];  // uniform broadcast
        const float4 hb = *(const float4*)&hs[w][1][j4 * 4];
        const float4 wrv = wr2[j4], wzv = wz2[j4], wnv = wn2[j4];
        DOT4(hr0, wrv, ha); DOT4(hz0, wzv, ha); DOT4(hn0, wnv, ha);
        DOT4(hr1, wrv, hb); DOT4(hz1, wzv, hb); DOT4(hn1, wnv, hb);
      }
      { float r = sigm(arA0 + hr0), z = sigm(azA0 + hz0);
        float n = tanhx(fmaf(r, hn0, anA0)); h0 = fmaf(z, h0 - n, n); }
      { float r = sigm(arA1 + hr1), z = sigm(azA1 + hz1);
        float n = tanhx(fmaf(r, hn1, anA1)); h1 = fmaf(z, h1 - n, n); }
      hs[w][0][l] = h0;   // own-wave write; in-order DS pipe orders vs step B reads
      hs[w][1][l] = h1;
    }
    // ---- step B ----
    {
      float hr0 = 0.f, hz0 = 0.f, hn0 = bhn2;
      float hr1 = 0.f, hz1 = 0.f, hn1 = bhn2;
#pragma unroll
      for (int j4 = 0; j4 < 16; ++j4) {
        const float4 ha = *(const float4*)&hs[w][0][j4 * 4];
        const float4 hb = *(const float4*)&hs[w][1][j4 * 4];
        const float4 wrv = wr2[j4], wzv = wz2[j4], wnv = wn2[j4];
        DOT4(hr0, wrv, ha); DOT4(hz0, wzv, ha); DOT4(hn0, wnv, ha);
        DOT4(hr1, wrv, hb); DOT4(hz1, wzv, hb); DOT4(hn1, wnv, hb);
      }
      { float r = sigm(arB0 + hr0), z = sigm(azB0 + hz0);
        float n = tanhx(fmaf(r, hn0, anB0)); h0 = fmaf(z, h0 - n, n); }
      { float r = sigm(arB1 + hr1), z = sigm(azB1 + hz1);
        float n = tanhx(fmaf(r, hn1, anB1)); h1 = fmaf(z, h1 - n, n); }
      hs[w][0][l] = h0;
      hs[w][1][l] = h1;
    }
  }
  __syncthreads();

  // ---------------- phase 3: h = h_fwd + h_bwd; MLP 64->32->8; wave w -> elem w ----------------
  if (l < 32) {
    const int s = l;
    float acc = b1[s];
    const float4* w1r = (const float4*)(W1 + s * 64);
#pragma unroll
    for (int j4 = 0; j4 < 16; ++j4) {
      const float4 hv0 = *(const float4*)&hs[0][w][j4 * 4];  // fwd, elem w
      const float4 hv1 = *(const float4*)&hs[1][w][j4 * 4];  // bwd, elem w
      const float4 wv  = w1r[j4];
      acc = fmaf(wv.x, hv0.x + hv1.x, acc);
      acc = fmaf(wv.y, hv0.y + hv1.y, acc);
      acc = fmaf(wv.z, hv0.z + hv1.z, acc);
      acc = fmaf(wv.w, hv0.w + hv1.w, acc);
    }
    ys[w][s] = acc;
  }
  // same-wave LDS write->read: in-order, no barrier needed
  if (l < 8) {
    float acc = b2[l];
#pragma unroll
    for (int j4 = 0; j4 < 8; ++j4) {
      const float4 yv = *(const float4*)&ys[w][j4 * 4];
      const float4 wv = *(const float4*)&W2[l * 32 + j4 * 4];
      DOT4(acc, wv, yv);
    }
    zout[(b0 + w) * 8 + l] = acc;
  }
}

extern "C" void kernel_launch(void* const* d_in, const int* in_sizes, int n_in,
                              void* d_out, int out_size, void* d_ws, size_t ws_size,
                              hipStream_t stream) {
  const float* all_traj = (const float*)d_in[0];
  const float* w_ih1  = (const float*)d_in[1];
  const float* w_hh1  = (const float*)d_in[2];
  const float* b_ih1  = (const float*)d_in[3];
  const float* b_hh1  = (const float*)d_in[4];
  const float* w_ih2f = (const float*)d_in[5];
  const float* w_hh2f = (const float*)d_in[6];
  const float* b_ih2f = (const float*)d_in[7];
  const float* b_hh2f = (const float*)d_in[8];
  const float* w_ih2b = (const float*)d_in[9];
  const float* w_hh2b = (const float*)d_in[10];
  const float* b_ih2b = (const float*)d_in[11];
  const float* b_hh2b = (const float*)d_in[12];
  const float* W1 = (const float*)d_in[13];
  const float* b1 = (const float*)d_in[14];
  const float* W2 = (const float*)d_in[15];
  const float* b2 = (const float*)d_in[16];
  float* z = (float*)d_out;

  // 2048 blocks x 128 threads (2 waves): wave = direction, 2 elements per wave
  gru_fused<<<BB / EPB, 128, 0, stream>>>(
      all_traj, w_ih1, w_hh1, b_ih1, b_hh1,
      w_ih2f, w_hh2f, b_ih2f, b_hh2f,
      w_ih2b, w_hh2b, b_ih2b, b_hh2b,
      W1, b1, W2, b2, z);
}